// Round 1
// 214.334 us; speedup vs baseline: 1.0751x; 1.0751x over previous
//
#include <hip/hip_runtime.h>

// GeometryTransformation: backproject(theta=0) -> 2x resblock(conv3d 16->16 3^3,
// InstanceNorm, ReLU, residual) -> forward-project at theta in {0, pi/2}.
//
// Round-9: LDS-staged mini conv. The mini MFMA path previously issued 36
// predicated global dwordx4 loads per lane (151 MB/layer, 9x redundancy on an
// 8 MB volume that does not fit a per-XCD L2). Now each block stages its
// 3 z-planes x 18 y-rows (27.6 KB) into LDS once (coalesced uint4), and the
// B-fragments come from ds_read_b128 (addresses form 2-lane broadcast pairs,
// bank coverage uniform). Global mini reads: 151 MB -> 28 MB per layer.
// Also merged wprep_k+prep_k into one kernel (prep sniffs the dtype flag
// locally), removing one serialized launch.
// Math identical to round-8 (passed, absmax 4.0): staged zeros reproduce the
// old row-validity predication exactly.

typedef unsigned short u16;
typedef unsigned int   u32;
using s16x8 = __attribute__((ext_vector_type(8))) short;
using f32x4 = __attribute__((ext_vector_type(4))) float;

#define IN_ELEMS 262144        // 128*128*16 fp32 interior
#define MN_ELEMS 4194304       // 128*128*16*16 u16 mini
#define WS_NEED  28505408ull

__device__ __forceinline__ float bf2f(u16 h) {
    union { u32 u; float f; } v; v.u = ((u32)h) << 16; return v.f;
}
__device__ __forceinline__ u16 f2bf(float f) {
    union { float f; u32 u; } v; v.f = f;
    u32 u = v.u;
    return (u16)((u + 0x7fffu + ((u >> 16) & 1u)) >> 16);
}
__device__ __forceinline__ float ldin(const void* p, int i, int bf) {
    return bf ? bf2f(((const u16*)p)[i]) : ((const float*)p)[i];
}
__device__ __forceinline__ u16 ldbf(const void* p, int i, int bf) {
    return bf ? ((const u16*)p)[i] : f2bf(((const float*)p)[i]);
}
__device__ __forceinline__ void unpack8(uint4 a, float* f) {
    u32 w[4] = {a.x, a.y, a.z, a.w};
#pragma unroll
    for (int i = 0; i < 4; i++) {
        f[2*i]   = bf2f((u16)(w[i] & 0xffff));
        f[2*i+1] = bf2f((u16)(w[i] >> 16));
    }
}
__device__ __forceinline__ void unpack4(uint2 a, float* f) {
    f[0] = bf2f((u16)(a.x & 0xffff)); f[1] = bf2f((u16)(a.x >> 16));
    f[2] = bf2f((u16)(a.y & 0xffff)); f[3] = bf2f((u16)(a.y >> 16));
}

__global__ void sentinel_k(u16* __restrict__ out, int n)
{
    int i = blockIdx.x * 256 + threadIdx.x;
    if (i < n) out[i] = 0x4640;
}

// ---------------------------------------------------------------------------
// Merged one-shot prep. 647 blocks:
//  0..17  : afrag[L][fi][lane][8]  (4608 lane-frags, MFMA A operands)
//  18     : st zero + flag + biasf
//  19..98 : zero P/PS/P0 (20480 floats)
//  99..134: w2d[L][tap9][ci][co] kx-summed fp32
//  135..646: layer-0 state (interior fp32 + mini bf16), old prep_k.
// Flag is sniffed locally per block (no cross-kernel dependency).
// ---------------------------------------------------------------------------
__global__ __launch_bounds__(256) void wprep_prep_k(
    const void* __restrict__ w0, const void* __restrict__ w1,
    const void* __restrict__ w2, const void* __restrict__ w3,
    const void* __restrict__ b0, const void* __restrict__ b1,
    const void* __restrict__ b2, const void* __restrict__ b3,
    const void* __restrict__ proj,
    float* __restrict__ st, int* __restrict__ flag,
    float* __restrict__ biasf, float* __restrict__ w2d,
    float* __restrict__ pz, u16* __restrict__ afrag,
    float* __restrict__ I0, u16* __restrict__ M0)
{
    const int tid = threadIdx.x;
    const u16* pp = (const u16*)w0;
    int cnt = 0;
    for (int i = 0; i < 32; i++) {
        int e = (pp[2 * i] >> 7) & 0xFF;
        if (e >= 64 && e <= 130) cnt++;
    }
    const int bf = (cnt >= 24) ? 1 : 0;
    const void* WS[4] = {w0, w1, w2, w3};
    const void* BS[4] = {b0, b1, b2, b3};
    const int b = blockIdx.x;

    if (b >= 135) {
        // ---- layer-0 state (old prep_k), 512 blocks ----
        const int bb = b - 135;
        const int d = bb >> 2;
        const int ys = (bb & 3) * 32;
        for (int i = tid; i < 512; i += 256) {
            int y = ys + (i >> 4), c = i & 15;
            I0[(d * 128 + y) * 16 + c] = ldin(proj, c * 16384 + d * 128 + y, bf);
        }
        for (int i = tid; i < 1024; i += 256) {
            int y = ys + (i >> 5), x = (i >> 1) & 15, hh = i & 1;
            bool on = (x <= 4) | (x == 7) | (x >= 8 && x < 12);
            u32 pw[4] = {0u, 0u, 0u, 0u};
            if (on) {
#pragma unroll
                for (int j = 0; j < 4; j++) {
                    int c0 = hh * 8 + 2 * j;
                    u16 a = f2bf(ldin(proj, c0 * 16384 + d * 128 + y, bf));
                    u16 bb2 = f2bf(ldin(proj, (c0 + 1) * 16384 + d * 128 + y, bf));
                    pw[j] = (u32)a | ((u32)bb2 << 16);
                }
            }
            *(uint4*)(M0 + ((d * 128 + y) << 8) + (x << 4) + hh * 8) =
                make_uint4(pw[0], pw[1], pw[2], pw[3]);
        }
        return;
    }

    if (b < 18) {
        int gi = b * 256 + tid;               // < 4608
        int L = gi / 1152, r = gi - L * 1152;
        int fi = r >> 6, l = r & 63;
        int kzky = fi >> 1, grp = fi & 1;
        int kz = kzky / 3, ky = kzky % 3;
        int n = l & 15, g = l >> 4, h = g & 1, kxs = g >> 1;
        int kx = grp * 2 + kxs;
        u16 v[8];
#pragma unroll
        for (int e = 0; e < 8; e++) {
            int ci = h * 8 + e;
            v[e] = (kx <= 2) ? ldbf(WS[L], n * 432 + ci * 27 + kz * 9 + ky * 3 + kx, bf)
                             : (u16)0;
        }
#pragma unroll
        for (int e = 0; e < 8; e++) afrag[gi * 8 + e] = v[e];
    } else if (b == 18) {
        st[tid] = 0.f;
        if (tid == 0) *flag = bf;
        if (tid < 64) biasf[tid] = ldin(BS[tid >> 4], tid & 15, bf);
    } else if (b < 99) {
        int i = (b - 19) * 256 + tid;         // < 20480
        pz[i] = 0.f;
    } else {
        int gi = (b - 99) * 256 + tid;        // < 9216
        int L = gi / 2304, r = gi - L * 2304;
        int tap = r >> 8, ci = (r >> 4) & 15, co = r & 15;
        int kz = tap / 3, ky = tap % 3;
        float s = 0.f;
#pragma unroll
        for (int kx = 0; kx < 3; kx++)
            s += ldin(WS[L], (co * 16 + ci) * 27 + kz * 9 + ky * 3 + kx, bf);
        w2d[gi] = s;
    }
}

// ---------------------------------------------------------------------------
// Fused layer. Blocks 0..255: interior 2D conv, block=(d, y-half of 64).
// Blocks 256..1279: mini MFMA conv (z, yt), wave = 4y, B-fragments from an
// LDS-staged 3x18-row window. Both accumulate stats.
// ---------------------------------------------------------------------------
__global__ __launch_bounds__(256) void layer_k(
    const float* __restrict__ Iin, const u16* __restrict__ Min,
    const float* __restrict__ w2dL, const u16* __restrict__ afragL,
    const float* __restrict__ biasL,
    float* __restrict__ Iout, u16* __restrict__ Mout,
    float* __restrict__ st_out)
{
    // interior: wsl 2304 f | pin 3366 f | sred 32 f   (22808 B)
    // mini:     stage 54*256 u16 (27648 B) | sred 32 f (128 B)
    __shared__ __align__(16) char smem_raw[27776];
    const int tid = threadIdx.x;

    if (blockIdx.x < 256) {
        float* smem = (float*)smem_raw;
        float* wsl  = smem;
        float* pin  = smem + 2304;
        float* sred = smem + 5670;
        const int d  = blockIdx.x >> 1;
        const int y0 = (blockIdx.x & 1) * 64;
        if (tid < 32) sred[tid] = 0.f;
        for (int i = tid; i < 2304; i += 256) wsl[i] = w2dL[i];
        for (int i = tid; i < 3168; i += 256) {
            int p = i / 1056, r = i - p * 1056;
            int row = r >> 4, c = r & 15;
            int zz = d + p - 1, gy = y0 + row - 1;
            float v = 0.f;
            if ((unsigned)zz < 128u && (unsigned)gy < 128u)
                v = Iin[(zz * 128 + gy) * 16 + c];
            pin[p * 1122 + row * 17 + c] = v;
        }
        __syncthreads();

        const int yl = tid & 63, h = tid >> 6;
        float acc[4];
#pragma unroll
        for (int cc = 0; cc < 4; cc++) acc[cc] = biasL[h * 4 + cc];
#pragma unroll
        for (int kz = 0; kz < 3; kz++) {
#pragma unroll
            for (int ky = 0; ky < 3; ky++) {
                const float* rowb = &pin[kz * 1122 + (yl + ky) * 17];
                const float* wrow = &wsl[(kz * 3 + ky) * 256 + h * 4];
#pragma unroll
                for (int ci = 0; ci < 16; ci++) {
                    float v = rowb[ci];
#pragma unroll
                    for (int cc = 0; cc < 4; cc++)
                        acc[cc] = fmaf(v, wrow[ci * 16 + cc], acc[cc]);
                }
            }
        }
        const int e = (d * 128 + y0 + yl) * 16 + h * 4;
        *(float4*)(Iout + e) = make_float4(acc[0], acc[1], acc[2], acc[3]);
        float s[4], q[4];
#pragma unroll
        for (int cc = 0; cc < 4; cc++) { s[cc] = acc[cc]; q[cc] = acc[cc] * acc[cc]; }
#pragma unroll
        for (int off = 1; off < 64; off <<= 1) {
#pragma unroll
            for (int cc = 0; cc < 4; cc++) {
                s[cc] += __shfl_down(s[cc], off, 64);
                q[cc] += __shfl_down(q[cc], off, 64);
            }
        }
        if ((tid & 63) == 0) {
#pragma unroll
            for (int cc = 0; cc < 4; cc++) {
                atomicAdd(&sred[h * 4 + cc], s[cc]);
                atomicAdd(&sred[16 + h * 4 + cc], q[cc]);
            }
        }
        __syncthreads();
        if (tid < 32) atomicAdd(&st_out[tid], 120.f * sred[tid]);
        return;
    }

    // ---------------- mini path ----------------
    u16*   stage = (u16*)smem_raw;
    float* sred  = (float*)(smem_raw + 27648);
    const int mb = blockIdx.x - 256;
    const int z  = mb & 127;
    const int yt = mb >> 7;
    const int l = tid & 63, w = tid >> 6;
    const int n = l & 15, g = l >> 4, h = g & 1, kxs = g >> 1;
    const int y0 = yt * 16 + w * 4;
    const int y0b = yt * 16;

    if (tid < 32) sred[tid] = 0.f;

    s16x8 af[18];
#pragma unroll
    for (int fi = 0; fi < 18; fi++)
        af[fi] = *(const s16x8*)(afragL + (fi * 64 + l) * 8);
    f32x4 binit = *(const f32x4*)(biasL + g * 4);

    // Stage 54 rows (3 z-planes x 18 y-rows), 512B each, coalesced.
    // OOB rows are zeroed -> reproduces the old per-load row predication.
    for (int i = tid; i < 1728; i += 256) {
        int r = i >> 5, p = i & 31;
        int kz = r / 18, yr = r - kz * 18;
        int gz = z + kz - 1, gy = y0b + yr - 1;
        uint4 v = make_uint4(0u, 0u, 0u, 0u);
        if (((unsigned)gz < 128u) & ((unsigned)gy < 128u))
            v = *(const uint4*)(Min + (((gz << 7) + gy) << 8) + p * 8);
        *(uint4*)(stage + r * 256 + p * 8) = v;
    }
    __syncthreads();

    f32x4 acc[4];
#pragma unroll
    for (int yl = 0; yl < 4; yl++) acc[yl] = binit;

    const int x0c = n + kxs - 1;
    const int x1c = x0c + 2;
    const bool v0ok = (unsigned)x0c < 16u;
    const bool v1ok = (unsigned)x1c < 16u;

#pragma unroll
    for (int kz = 0; kz < 3; kz++) {
#pragma unroll
        for (int yin = 0; yin < 6; yin++) {
            const u16* rowp = stage + (kz * 18 + (w << 2) + yin) * 256 + h * 8;
            uint4 q0 = make_uint4(0u, 0u, 0u, 0u);
            uint4 q1 = make_uint4(0u, 0u, 0u, 0u);
            if (v0ok) q0 = *(const uint4*)(rowp + (x0c << 4));
            if (v1ok) q1 = *(const uint4*)(rowp + (x1c << 4));
            s16x8 f0 = __builtin_bit_cast(s16x8, q0);
            s16x8 f1 = __builtin_bit_cast(s16x8, q1);
#pragma unroll
            for (int ky = 0; ky < 3; ky++) {
                const int yl = yin - ky;
                if (yl >= 0 && yl < 4) {
                    acc[yl] = __builtin_amdgcn_mfma_f32_16x16x32_bf16(af[(kz * 3 + ky) * 2],     f0, acc[yl], 0, 0, 0);
                    acc[yl] = __builtin_amdgcn_mfma_f32_16x16x32_bf16(af[(kz * 3 + ky) * 2 + 1], f1, acc[yl], 0, 0, 0);
                }
            }
        }
    }

    const float inc = (((n >> 2) & 1) == 0) ? 1.f : 0.f;
    float sr[4] = {0.f, 0.f, 0.f, 0.f}, qr[4] = {0.f, 0.f, 0.f, 0.f};
#pragma unroll
    for (int yl = 0; yl < 4; yl++) {
        const int gy = y0 + yl;
        u32 lo = (u32)f2bf(acc[yl][0]) | ((u32)f2bf(acc[yl][1]) << 16);
        u32 hi = (u32)f2bf(acc[yl][2]) | ((u32)f2bf(acc[yl][3]) << 16);
        *(uint2*)(Mout + (((z << 7) + gy) << 8) + (n << 4) + g * 4) = make_uint2(lo, hi);
#pragma unroll
        for (int r = 0; r < 4; r++) {
            sr[r] += inc * acc[yl][r];
            qr[r] = fmaf(inc * acc[yl][r], acc[yl][r], qr[r]);
        }
    }
#pragma unroll
    for (int off = 1; off < 16; off <<= 1) {
#pragma unroll
        for (int r = 0; r < 4; r++) {
            sr[r] += __shfl_down(sr[r], off, 16);
            qr[r] += __shfl_down(qr[r], off, 16);
        }
    }
    __syncthreads();
    if (n == 0) {
#pragma unroll
        for (int r = 0; r < 4; r++) {
            atomicAdd(&sred[g * 4 + r], sr[r]);
            atomicAdd(&sred[16 + g * 4 + r], qr[r]);
        }
    }
    __syncthreads();
    if (tid < 32) atomicAdd(&st_out[tid], sred[tid]);
}

// Streaming normalize (512 blocks): m,s from raw sums; RES adds vol0(=proj).
template <int RES>
__global__ __launch_bounds__(256) void norm_k(
    const float* __restrict__ Iraw, const u16* __restrict__ Mraw,
    const void* __restrict__ proj, const float* __restrict__ stL,
    const int* __restrict__ flagp,
    float* __restrict__ Iout, u16* __restrict__ Mout)
{
    __shared__ float sA[32];
    const int bf = *flagp;
    const int d  = blockIdx.x >> 2;
    const int ys = (blockIdx.x & 3) * 32;
    const int tid = threadIdx.x;
    if (tid < 32) {
        const float inv = 1.f / 2097152.f;
        int c = tid & 15;
        float m = stL[c] * inv;
        sA[tid] = (tid < 16) ? m : rsqrtf(stL[16 + c] * inv - m * m + 1e-5f);
    }
    __syncthreads();
    for (int i = tid; i < 512; i += 256) {
        int y = ys + (i >> 4), c = i & 15;
        float res = RES ? ldin(proj, c * 16384 + d * 128 + y, bf) : 0.f;
        float v = fmaxf((Iraw[(d * 128 + y) * 16 + c] - sA[c]) * sA[16 + c] + res, 0.f);
        Iout[(d * 128 + y) * 16 + c] = v;
    }
    for (int i = tid; i < 1024; i += 256) {
        int y = ys + (i >> 5), x = (i >> 1) & 15, hh = i & 1;
        bool realc = (x < 4) | (x >= 8 && x < 12);
        bool ghost = (x == 4) | (x == 7);
        u32 pw[4] = {0u, 0u, 0u, 0u};
        if (realc | ghost) {
            float f[8];
            if (realc) {
                uint4 raw = *(const uint4*)(Mraw + ((d * 128 + y) << 8) + (x << 4) + hh * 8);
                unpack8(raw, f);
            } else {
#pragma unroll
                for (int j = 0; j < 8; j++)
                    f[j] = Iraw[(d * 128 + y) * 16 + hh * 8 + j];
            }
            float vals[8];
#pragma unroll
            for (int j = 0; j < 8; j++) {
                int c = hh * 8 + j;
                float res = RES ? ldin(proj, c * 16384 + d * 128 + y, bf) : 0.f;
                vals[j] = fmaxf((f[j] - sA[c]) * sA[16 + c] + res, 0.f);
            }
#pragma unroll
            for (int j = 0; j < 4; j++)
                pw[j] = (u32)f2bf(vals[2*j]) | ((u32)f2bf(vals[2*j+1]) << 16);
        }
        *(uint4*)(Mout + ((d * 128 + y) << 8) + (x << 4) + hh * 8) =
            make_uint4(pw[0], pw[1], pw[2], pw[3]);
    }
}

// fproj stage 1: 256 blocks = (d, y-half). vol2 = relu((y4-m)s + xb).
// Writes theta=0 row sums directly; accumulates column partials:
//   P[d][j][c]  (8 mini cols), PS[d][c] (interior Sum_y v2d),
//   P0[d][c] = y<64 partial of col j=0 (written by half-0 only).
__global__ __launch_bounds__(256) void fproj1_k(
    const float* __restrict__ I4, const float* __restrict__ IXB,
    const u16* __restrict__ M4, const u16* __restrict__ MXB,
    const float* __restrict__ stL, const int* __restrict__ flagp,
    void* __restrict__ out,
    float* __restrict__ P, float* __restrict__ PS, float* __restrict__ P0)
{
    __shared__ float sA[32];
    const int bf = *flagp;
    const int d = blockIdx.x >> 1;
    const int half = blockIdx.x & 1;
    const int tid = threadIdx.x;
    if (tid < 32) {
        const float inv = 1.f / 2097152.f;
        int c = tid & 15;
        float m = stL[c] * inv;
        sA[tid] = (tid < 16) ? m : rsqrtf(stL[16 + c] * inv - m * m + 1e-5f);
    }
    __syncthreads();

    const int yl = tid & 63, y = half * 64 + yl;
    const int h = tid >> 6, c0 = h * 4;

    float v2d[4], row[4];
    {
        const int e = (d * 128 + y) * 16 + c0;
        float4 a = *(const float4*)(I4 + e);
        float4 x = *(const float4*)(IXB + e);
        float ia[4] = {a.x, a.y, a.z, a.w};
        float xa[4] = {x.x, x.y, x.z, x.w};
#pragma unroll
        for (int cc = 0; cc < 4; cc++) {
            int c = c0 + cc;
            v2d[cc] = fmaxf((ia[cc] - sA[c]) * sA[16 + c] + xa[cc], 0.f);
            row[cc] = 120.f * v2d[cc];
        }
    }
    float colp[8][4];
#pragma unroll
    for (int j = 0; j < 8; j++) {
        const int m = (j < 4) ? j : j + 4;
        const int e = ((d * 128 + y) << 8) + (m << 4) + c0;
        float f4[4], fx[4];
        unpack4(*(const uint2*)(M4 + e), f4);
        unpack4(*(const uint2*)(MXB + e), fx);
#pragma unroll
        for (int cc = 0; cc < 4; cc++) {
            int c = c0 + cc;
            float v = fmaxf((f4[cc] - sA[c]) * sA[16 + c] + fx[cc], 0.f);
            row[cc] += v;
            colp[j][cc] = v;
        }
    }
#pragma unroll
    for (int cc = 0; cc < 4; cc++) {
        int oi = ((c0 + cc) * 2) * 16384 + d * 128 + y;
        if (bf) ((u16*)out)[oi] = f2bf(row[cc]); else ((float*)out)[oi] = row[cc];
    }
#pragma unroll
    for (int off = 1; off < 64; off <<= 1) {
#pragma unroll
        for (int cc = 0; cc < 4; cc++) {
            v2d[cc] += __shfl_down(v2d[cc], off, 64);
#pragma unroll
            for (int j = 0; j < 8; j++)
                colp[j][cc] += __shfl_down(colp[j][cc], off, 64);
        }
    }
    if (yl == 0) {
#pragma unroll
        for (int cc = 0; cc < 4; cc++) {
            atomicAdd(&PS[d * 16 + c0 + cc], v2d[cc]);
#pragma unroll
            for (int j = 0; j < 8; j++)
                atomicAdd(&P[(d * 8 + j) * 16 + c0 + cc], colp[j][cc]);
            if (half == 0) P0[d * 16 + c0 + cc] = colp[0][cc];
        }
    }
}

// fproj stage 2: expand partials into theta=pi/2 outputs.
__global__ __launch_bounds__(256) void fproj2_k(
    const float* __restrict__ P, const float* __restrict__ PS,
    const float* __restrict__ P0, const int* __restrict__ flagp,
    void* __restrict__ out)
{
    const int bf = *flagp;
    const int d = blockIdx.x;
    const int tid = threadIdx.x;
    for (int i = tid; i < 2048; i += 256) {
        int c = i >> 7, u = i & 127;
        float v;
        if (u == 0)        v = P0[d * 16 + c];
        else if (u < 4)    v = P[(d * 8 + u) * 16 + c];
        else if (u >= 124) v = P[(d * 8 + (u - 120)) * 16 + c];
        else               v = PS[d * 16 + c];
        int oi = (c * 2 + 1) * 16384 + d * 128 + u;
        if (bf) ((u16*)out)[oi] = f2bf(v); else ((float*)out)[oi] = v;
    }
}

extern "C" void kernel_launch(void* const* d_in, const int* in_sizes, int n_in,
                              void* d_out, int out_size, void* d_ws, size_t ws_size,
                              hipStream_t stream)
{
    if (ws_size < WS_NEED) {
        sentinel_k<<<(out_size + 255) / 256, 256, 0, stream>>>((u16*)d_out, out_size);
        return;
    }
    const void* proj = d_in[0];
    const void* w1 = d_in[1]; const void* b1 = d_in[2];
    const void* w2 = d_in[3]; const void* b2 = d_in[4];
    const void* w3 = d_in[5]; const void* b3 = d_in[6];
    const void* w4 = d_in[7]; const void* b4 = d_in[8];

    float* I_A  = (float*)d_ws;
    float* I_B  = I_A + IN_ELEMS;
    float* I_XB = I_B + IN_ELEMS;
    u16*   M_A  = (u16*)(I_XB + IN_ELEMS);
    u16*   M_B  = M_A + MN_ELEMS;
    u16*   M_XB = M_B + MN_ELEMS;
    float* st    = (float*)(M_XB + MN_ELEMS);   // 256
    int*   flag  = (int*)(st + 256);            // 16
    float* biasf = (float*)(flag + 16);         // 64
    float* w2d   = biasf + 64;                  // 9216
    float* P     = w2d + 9216;                  // 16384
    float* PS    = P + 16384;                   // 2048
    float* P0    = PS + 2048;                   // 2048
    u16*   afrag = (u16*)(P0 + 2048);           // 36864

    wprep_prep_k<<<647, 256, 0, stream>>>(w1, w2, w3, w4, b1, b2, b3, b4, proj,
                                          st, flag, biasf, w2d, P, afrag, I_A, M_A);

    dim3 lg(1280), cb(256);
    // L1
    layer_k<<<lg, cb, 0, stream>>>(I_A, M_A, w2d + 0,    afrag + 0,     biasf + 0,  I_B, M_B, st + 0);
    norm_k<0><<<512, cb, 0, stream>>>(I_B, M_B, proj, st + 0, flag, I_A, M_A);
    // L2
    layer_k<<<lg, cb, 0, stream>>>(I_A, M_A, w2d + 2304, afrag + 9216,  biasf + 16, I_B, M_B, st + 64);
    norm_k<1><<<512, cb, 0, stream>>>(I_B, M_B, proj, st + 64, flag, I_XB, M_XB);
    // L3
    layer_k<<<lg, cb, 0, stream>>>(I_XB, M_XB, w2d + 4608, afrag + 18432, biasf + 32, I_B, M_B, st + 128);
    norm_k<0><<<512, cb, 0, stream>>>(I_B, M_B, proj, st + 128, flag, I_A, M_A);
    // L4
    layer_k<<<lg, cb, 0, stream>>>(I_A, M_A, w2d + 6912, afrag + 27648, biasf + 48, I_B, M_B, st + 192);
    // projection
    fproj1_k<<<256, cb, 0, stream>>>(I_B, I_XB, M_B, M_XB, st + 192, flag, d_out, P, PS, P0);
    fproj2_k<<<128, cb, 0, stream>>>(P, PS, P0, flag, d_out);
}

// Round 2
// 211.441 us; speedup vs baseline: 1.0898x; 1.0137x over previous
//
#include <hip/hip_runtime.h>

// GeometryTransformation: backproject(theta=0) -> 2x resblock(conv3d 16->16 3^3,
// InstanceNorm, ReLU, residual) -> forward-project at theta in {0, pi/2}.
//
// Round-10: norm fused into layer staging. norm_k is gone: each layer_k<NORM,..>
// normalizes the PREVIOUS layer's raw output on the fly while staging (interior
// pin + mini LDS rows), reproducing norm_k's exact math: ghost cols (x=4,7)
// rebuilt from the interior field, zeros elsewhere, x-constant proj residual.
// L3 (<1,1,1>) additionally materializes XB (resblock-b input) from its owned
// non-halo region (kz==1, yr 1..16 / p==1, row 1..64) -- every (z,y) exactly
// once -- for fproj's residual. Dispatches 10 -> 7; removes ~50 MB of
// intermediate traffic and 3 launch/drain boundaries.
// Buffer flow: prep->A; L1 A->B; L2(norm st0) B->A; L3(norm st1,+proj,XB) A->B;
// wait no: L3 writes B? see launcher: L1 A->B, L2 B->A, L3 A->B(+XB), L4 B->A;
// fproj reads A(raw y4) + XB.
// Math identical to round-9 (passed, absmax 4.0).

typedef unsigned short u16;
typedef unsigned int   u32;
using s16x8 = __attribute__((ext_vector_type(8))) short;
using f32x4 = __attribute__((ext_vector_type(4))) float;

#define IN_ELEMS 262144        // 128*128*16 fp32 interior
#define MN_ELEMS 4194304       // 128*128*16*16 u16 mini
#define WS_NEED  28505408ull

__device__ __forceinline__ float bf2f(u16 h) {
    union { u32 u; float f; } v; v.u = ((u32)h) << 16; return v.f;
}
__device__ __forceinline__ u16 f2bf(float f) {
    union { float f; u32 u; } v; v.f = f;
    u32 u = v.u;
    return (u16)((u + 0x7fffu + ((u >> 16) & 1u)) >> 16);
}
__device__ __forceinline__ float ldin(const void* p, int i, int bf) {
    return bf ? bf2f(((const u16*)p)[i]) : ((const float*)p)[i];
}
__device__ __forceinline__ u16 ldbf(const void* p, int i, int bf) {
    return bf ? ((const u16*)p)[i] : f2bf(((const float*)p)[i]);
}
__device__ __forceinline__ void unpack8(uint4 a, float* f) {
    u32 w[4] = {a.x, a.y, a.z, a.w};
#pragma unroll
    for (int i = 0; i < 4; i++) {
        f[2*i]   = bf2f((u16)(w[i] & 0xffff));
        f[2*i+1] = bf2f((u16)(w[i] >> 16));
    }
}
__device__ __forceinline__ void unpack4(uint2 a, float* f) {
    f[0] = bf2f((u16)(a.x & 0xffff)); f[1] = bf2f((u16)(a.x >> 16));
    f[2] = bf2f((u16)(a.y & 0xffff)); f[3] = bf2f((u16)(a.y >> 16));
}

__global__ void sentinel_k(u16* __restrict__ out, int n)
{
    int i = blockIdx.x * 256 + threadIdx.x;
    if (i < n) out[i] = 0x4640;
}

// ---------------------------------------------------------------------------
// Merged one-shot prep. 647 blocks:
//  0..17  : afrag[L][fi][lane][8]  (4608 lane-frags, MFMA A operands)
//  18     : st zero + flag + biasf
//  19..98 : zero P/PS/P0 (20480 floats)
//  99..134: w2d[L][tap9][ci][co] kx-summed fp32
//  135..646: layer-0 state (interior fp32 + mini bf16).
// ---------------------------------------------------------------------------
__global__ __launch_bounds__(256) void wprep_prep_k(
    const void* __restrict__ w0, const void* __restrict__ w1,
    const void* __restrict__ w2, const void* __restrict__ w3,
    const void* __restrict__ b0, const void* __restrict__ b1,
    const void* __restrict__ b2, const void* __restrict__ b3,
    const void* __restrict__ proj,
    float* __restrict__ st, int* __restrict__ flag,
    float* __restrict__ biasf, float* __restrict__ w2d,
    float* __restrict__ pz, u16* __restrict__ afrag,
    float* __restrict__ I0, u16* __restrict__ M0)
{
    const int tid = threadIdx.x;
    const u16* pp = (const u16*)w0;
    int cnt = 0;
    for (int i = 0; i < 32; i++) {
        int e = (pp[2 * i] >> 7) & 0xFF;
        if (e >= 64 && e <= 130) cnt++;
    }
    const int bf = (cnt >= 24) ? 1 : 0;
    const void* WS[4] = {w0, w1, w2, w3};
    const void* BS[4] = {b0, b1, b2, b3};
    const int b = blockIdx.x;

    if (b >= 135) {
        const int bb = b - 135;
        const int d = bb >> 2;
        const int ys = (bb & 3) * 32;
        for (int i = tid; i < 512; i += 256) {
            int y = ys + (i >> 4), c = i & 15;
            I0[(d * 128 + y) * 16 + c] = ldin(proj, c * 16384 + d * 128 + y, bf);
        }
        for (int i = tid; i < 1024; i += 256) {
            int y = ys + (i >> 5), x = (i >> 1) & 15, hh = i & 1;
            bool on = (x <= 4) | (x == 7) | (x >= 8 && x < 12);
            u32 pw[4] = {0u, 0u, 0u, 0u};
            if (on) {
#pragma unroll
                for (int j = 0; j < 4; j++) {
                    int c0 = hh * 8 + 2 * j;
                    u16 a = f2bf(ldin(proj, c0 * 16384 + d * 128 + y, bf));
                    u16 bb2 = f2bf(ldin(proj, (c0 + 1) * 16384 + d * 128 + y, bf));
                    pw[j] = (u32)a | ((u32)bb2 << 16);
                }
            }
            *(uint4*)(M0 + ((d * 128 + y) << 8) + (x << 4) + hh * 8) =
                make_uint4(pw[0], pw[1], pw[2], pw[3]);
        }
        return;
    }

    if (b < 18) {
        int gi = b * 256 + tid;               // < 4608
        int L = gi / 1152, r = gi - L * 1152;
        int fi = r >> 6, l = r & 63;
        int kzky = fi >> 1, grp = fi & 1;
        int kz = kzky / 3, ky = kzky % 3;
        int n = l & 15, g = l >> 4, h = g & 1, kxs = g >> 1;
        int kx = grp * 2 + kxs;
        u16 v[8];
#pragma unroll
        for (int e = 0; e < 8; e++) {
            int ci = h * 8 + e;
            v[e] = (kx <= 2) ? ldbf(WS[L], n * 432 + ci * 27 + kz * 9 + ky * 3 + kx, bf)
                             : (u16)0;
        }
#pragma unroll
        for (int e = 0; e < 8; e++) afrag[gi * 8 + e] = v[e];
    } else if (b == 18) {
        st[tid] = 0.f;
        if (tid == 0) *flag = bf;
        if (tid < 64) biasf[tid] = ldin(BS[tid >> 4], tid & 15, bf);
    } else if (b < 99) {
        int i = (b - 19) * 256 + tid;         // < 20480
        pz[i] = 0.f;
    } else {
        int gi = (b - 99) * 256 + tid;        // < 9216
        int L = gi / 2304, r = gi - L * 2304;
        int tap = r >> 8, ci = (r >> 4) & 15, co = r & 15;
        int kz = tap / 3, ky = tap % 3;
        float s = 0.f;
#pragma unroll
        for (int kx = 0; kx < 3; kx++)
            s += ldin(WS[L], (co * 16 + ci) * 27 + kz * 9 + ky * 3 + kx, bf);
        w2d[gi] = s;
    }
}

// ---------------------------------------------------------------------------
// Fused layer. NORM: staging normalizes the raw previous-layer output with
// stP (exact norm_k math: ghosts from interior, zeros elsewhere). RES adds
// the x-constant proj residual. WXB: materialize XB from owned region.
// Blocks 0..255: interior 2D conv. Blocks 256..1279: mini MFMA conv.
// ---------------------------------------------------------------------------
template <int NORM, int RES, int WXB>
__global__ __launch_bounds__(256) void layer_k(
    const float* __restrict__ Iin, const u16* __restrict__ Min,
    const void* __restrict__ proj, const float* __restrict__ stP,
    const int* __restrict__ flagp,
    const float* __restrict__ w2dL, const u16* __restrict__ afragL,
    const float* __restrict__ biasL,
    float* __restrict__ Iout, u16* __restrict__ Mout,
    float* __restrict__ IXB, u16* __restrict__ MXB,
    float* __restrict__ st_out)
{
    // interior: wsl 2304 f | pin 3366 f | sred 32 f | sA 32 f (22936 B)
    // mini:     stage 54*256 u16 (27648 B) | sred 32 f | sA 32 f (27904 B)
    __shared__ __align__(16) char smem_raw[27904];
    const int tid = threadIdx.x;
    const int bf = RES ? *flagp : 0;

    if (blockIdx.x < 256) {
        float* smem = (float*)smem_raw;
        float* wsl  = smem;
        float* pin  = smem + 2304;
        float* sred = smem + 5670;
        float* sA   = smem + 5702;
        const int d  = blockIdx.x >> 1;
        const int y0 = (blockIdx.x & 1) * 64;
        if (tid < 32) {
            sred[tid] = 0.f;
            if (NORM) {
                const float inv = 1.f / 2097152.f;
                int c = tid & 15;
                float m = stP[c] * inv;
                sA[tid] = (tid < 16) ? m : rsqrtf(stP[16 + c] * inv - m * m + 1e-5f);
            }
        }
        for (int i = tid; i < 2304; i += 256) wsl[i] = w2dL[i];
        if (NORM) __syncthreads();           // sA ready before pin staging
        for (int i = tid; i < 3168; i += 256) {
            int p = i / 1056, r = i - p * 1056;
            int row = r >> 4, c = r & 15;
            int zz = d + p - 1, gy = y0 + row - 1;
            float v = 0.f;
            if ((unsigned)zz < 128u && (unsigned)gy < 128u) {
                v = Iin[(zz * 128 + gy) * 16 + c];
                if (NORM) {
                    float res = RES ? ldin(proj, c * 16384 + zz * 128 + gy, bf) : 0.f;
                    v = fmaxf((v - sA[c]) * sA[16 + c] + res, 0.f);
                }
                if (WXB && p == 1 && row >= 1 && row <= 64)
                    IXB[(d * 128 + gy) * 16 + c] = v;
            }
            pin[p * 1122 + row * 17 + c] = v;
        }
        __syncthreads();

        const int yl = tid & 63, h = tid >> 6;
        float acc[4];
#pragma unroll
        for (int cc = 0; cc < 4; cc++) acc[cc] = biasL[h * 4 + cc];
#pragma unroll
        for (int kz = 0; kz < 3; kz++) {
#pragma unroll
            for (int ky = 0; ky < 3; ky++) {
                const float* rowb = &pin[kz * 1122 + (yl + ky) * 17];
                const float* wrow = &wsl[(kz * 3 + ky) * 256 + h * 4];
#pragma unroll
                for (int ci = 0; ci < 16; ci++) {
                    float v = rowb[ci];
#pragma unroll
                    for (int cc = 0; cc < 4; cc++)
                        acc[cc] = fmaf(v, wrow[ci * 16 + cc], acc[cc]);
                }
            }
        }
        const int e = (d * 128 + y0 + yl) * 16 + h * 4;
        *(float4*)(Iout + e) = make_float4(acc[0], acc[1], acc[2], acc[3]);
        float s[4], q[4];
#pragma unroll
        for (int cc = 0; cc < 4; cc++) { s[cc] = acc[cc]; q[cc] = acc[cc] * acc[cc]; }
#pragma unroll
        for (int off = 1; off < 64; off <<= 1) {
#pragma unroll
            for (int cc = 0; cc < 4; cc++) {
                s[cc] += __shfl_down(s[cc], off, 64);
                q[cc] += __shfl_down(q[cc], off, 64);
            }
        }
        if ((tid & 63) == 0) {
#pragma unroll
            for (int cc = 0; cc < 4; cc++) {
                atomicAdd(&sred[h * 4 + cc], s[cc]);
                atomicAdd(&sred[16 + h * 4 + cc], q[cc]);
            }
        }
        __syncthreads();
        if (tid < 32) atomicAdd(&st_out[tid], 120.f * sred[tid]);
        return;
    }

    // ---------------- mini path ----------------
    u16*   stage = (u16*)smem_raw;
    float* sred  = (float*)(smem_raw + 27648);
    float* sA    = (float*)(smem_raw + 27776);
    const int mb = blockIdx.x - 256;
    const int z  = mb & 127;
    const int yt = mb >> 7;
    const int l = tid & 63, w = tid >> 6;
    const int n = l & 15, g = l >> 4, h = g & 1, kxs = g >> 1;
    const int y0 = yt * 16 + w * 4;
    const int y0b = yt * 16;

    if (tid < 32) {
        sred[tid] = 0.f;
        if (NORM) {
            const float inv = 1.f / 2097152.f;
            int c = tid & 15;
            float m = stP[c] * inv;
            sA[tid] = (tid < 16) ? m : rsqrtf(stP[16 + c] * inv - m * m + 1e-5f);
        }
    }
    if (NORM) __syncthreads();               // sA ready before staging

    // Stage 54 rows (3 z-planes x 18 y-rows), 512B each. NORM applies the
    // fused normalize (ghosts x=4,7 from interior; zeros elsewhere).
    for (int i = tid; i < 1728; i += 256) {
        int r = i >> 5, p = i & 31;
        int kz = r / 18, yr = r - kz * 18;
        int gz = z + kz - 1, gy = y0b + yr - 1;
        uint4 v = make_uint4(0u, 0u, 0u, 0u);
        bool inb = ((unsigned)gz < 128u) & ((unsigned)gy < 128u);
        if (!NORM) {
            if (inb) v = *(const uint4*)(Min + (((gz << 7) + gy) << 8) + p * 8);
        } else {
            int x = p >> 1, hh = p & 1;
            bool realc = (x < 4) | (x >= 8 && x < 12);
            bool ghost = (x == 4) | (x == 7);
            if (inb & (realc | ghost)) {
                float f[8];
                if (realc) {
                    uint4 raw = *(const uint4*)(Min + (((gz << 7) + gy) << 8) + p * 8);
                    unpack8(raw, f);
                } else {
                    const float* ip = Iin + ((gz * 128 + gy) * 16 + hh * 8);
                    float4 a  = *(const float4*)(ip);
                    float4 b2 = *(const float4*)(ip + 4);
                    f[0] = a.x;  f[1] = a.y;  f[2] = a.z;  f[3] = a.w;
                    f[4] = b2.x; f[5] = b2.y; f[6] = b2.z; f[7] = b2.w;
                }
                float vals[8];
#pragma unroll
                for (int j = 0; j < 8; j++) {
                    int c = hh * 8 + j;
                    float res = RES ? ldin(proj, c * 16384 + gz * 128 + gy, bf) : 0.f;
                    vals[j] = fmaxf((f[j] - sA[c]) * sA[16 + c] + res, 0.f);
                }
                u32 pw[4];
#pragma unroll
                for (int j = 0; j < 4; j++)
                    pw[j] = (u32)f2bf(vals[2*j]) | ((u32)f2bf(vals[2*j+1]) << 16);
                v = make_uint4(pw[0], pw[1], pw[2], pw[3]);
            }
            if (WXB && kz == 1 && yr >= 1 && yr <= 16)
                *(uint4*)(MXB + (((z << 7) + gy) << 8) + p * 8) = v;
        }
        *(uint4*)(stage + r * 256 + p * 8) = v;
    }

    s16x8 af[18];
#pragma unroll
    for (int fi = 0; fi < 18; fi++)
        af[fi] = *(const s16x8*)(afragL + (fi * 64 + l) * 8);
    f32x4 binit = *(const f32x4*)(biasL + g * 4);
    __syncthreads();

    f32x4 acc[4];
#pragma unroll
    for (int yl = 0; yl < 4; yl++) acc[yl] = binit;

    const int x0c = n + kxs - 1;
    const int x1c = x0c + 2;
    const bool v0ok = (unsigned)x0c < 16u;
    const bool v1ok = (unsigned)x1c < 16u;

#pragma unroll
    for (int kz = 0; kz < 3; kz++) {
#pragma unroll
        for (int yin = 0; yin < 6; yin++) {
            const u16* rowp = stage + (kz * 18 + (w << 2) + yin) * 256 + h * 8;
            uint4 q0 = make_uint4(0u, 0u, 0u, 0u);
            uint4 q1 = make_uint4(0u, 0u, 0u, 0u);
            if (v0ok) q0 = *(const uint4*)(rowp + (x0c << 4));
            if (v1ok) q1 = *(const uint4*)(rowp + (x1c << 4));
            s16x8 f0 = __builtin_bit_cast(s16x8, q0);
            s16x8 f1 = __builtin_bit_cast(s16x8, q1);
#pragma unroll
            for (int ky = 0; ky < 3; ky++) {
                const int yl = yin - ky;
                if (yl >= 0 && yl < 4) {
                    acc[yl] = __builtin_amdgcn_mfma_f32_16x16x32_bf16(af[(kz * 3 + ky) * 2],     f0, acc[yl], 0, 0, 0);
                    acc[yl] = __builtin_amdgcn_mfma_f32_16x16x32_bf16(af[(kz * 3 + ky) * 2 + 1], f1, acc[yl], 0, 0, 0);
                }
            }
        }
    }

    const float inc = (((n >> 2) & 1) == 0) ? 1.f : 0.f;
    float sr[4] = {0.f, 0.f, 0.f, 0.f}, qr[4] = {0.f, 0.f, 0.f, 0.f};
#pragma unroll
    for (int yl = 0; yl < 4; yl++) {
        const int gy = y0 + yl;
        u32 lo = (u32)f2bf(acc[yl][0]) | ((u32)f2bf(acc[yl][1]) << 16);
        u32 hi = (u32)f2bf(acc[yl][2]) | ((u32)f2bf(acc[yl][3]) << 16);
        *(uint2*)(Mout + (((z << 7) + gy) << 8) + (n << 4) + g * 4) = make_uint2(lo, hi);
#pragma unroll
        for (int r = 0; r < 4; r++) {
            sr[r] += inc * acc[yl][r];
            qr[r] = fmaf(inc * acc[yl][r], acc[yl][r], qr[r]);
        }
    }
#pragma unroll
    for (int off = 1; off < 16; off <<= 1) {
#pragma unroll
        for (int r = 0; r < 4; r++) {
            sr[r] += __shfl_down(sr[r], off, 16);
            qr[r] += __shfl_down(qr[r], off, 16);
        }
    }
    __syncthreads();
    if (n == 0) {
#pragma unroll
        for (int r = 0; r < 4; r++) {
            atomicAdd(&sred[g * 4 + r], sr[r]);
            atomicAdd(&sred[16 + g * 4 + r], qr[r]);
        }
    }
    __syncthreads();
    if (tid < 32) atomicAdd(&st_out[tid], sred[tid]);
}

// fproj stage 1: 256 blocks = (d, y-half). vol2 = relu((y4-m)s + xb).
__global__ __launch_bounds__(256) void fproj1_k(
    const float* __restrict__ I4, const float* __restrict__ IXB,
    const u16* __restrict__ M4, const u16* __restrict__ MXB,
    const float* __restrict__ stL, const int* __restrict__ flagp,
    void* __restrict__ out,
    float* __restrict__ P, float* __restrict__ PS, float* __restrict__ P0)
{
    __shared__ float sA[32];
    const int bf = *flagp;
    const int d = blockIdx.x >> 1;
    const int half = blockIdx.x & 1;
    const int tid = threadIdx.x;
    if (tid < 32) {
        const float inv = 1.f / 2097152.f;
        int c = tid & 15;
        float m = stL[c] * inv;
        sA[tid] = (tid < 16) ? m : rsqrtf(stL[16 + c] * inv - m * m + 1e-5f);
    }
    __syncthreads();

    const int yl = tid & 63, y = half * 64 + yl;
    const int h = tid >> 6, c0 = h * 4;

    float v2d[4], row[4];
    {
        const int e = (d * 128 + y) * 16 + c0;
        float4 a = *(const float4*)(I4 + e);
        float4 x = *(const float4*)(IXB + e);
        float ia[4] = {a.x, a.y, a.z, a.w};
        float xa[4] = {x.x, x.y, x.z, x.w};
#pragma unroll
        for (int cc = 0; cc < 4; cc++) {
            int c = c0 + cc;
            v2d[cc] = fmaxf((ia[cc] - sA[c]) * sA[16 + c] + xa[cc], 0.f);
            row[cc] = 120.f * v2d[cc];
        }
    }
    float colp[8][4];
#pragma unroll
    for (int j = 0; j < 8; j++) {
        const int m = (j < 4) ? j : j + 4;
        const int e = ((d * 128 + y) << 8) + (m << 4) + c0;
        float f4[4], fx[4];
        unpack4(*(const uint2*)(M4 + e), f4);
        unpack4(*(const uint2*)(MXB + e), fx);
#pragma unroll
        for (int cc = 0; cc < 4; cc++) {
            int c = c0 + cc;
            float v = fmaxf((f4[cc] - sA[c]) * sA[16 + c] + fx[cc], 0.f);
            row[cc] += v;
            colp[j][cc] = v;
        }
    }
#pragma unroll
    for (int cc = 0; cc < 4; cc++) {
        int oi = ((c0 + cc) * 2) * 16384 + d * 128 + y;
        if (bf) ((u16*)out)[oi] = f2bf(row[cc]); else ((float*)out)[oi] = row[cc];
    }
#pragma unroll
    for (int off = 1; off < 64; off <<= 1) {
#pragma unroll
        for (int cc = 0; cc < 4; cc++) {
            v2d[cc] += __shfl_down(v2d[cc], off, 64);
#pragma unroll
            for (int j = 0; j < 8; j++)
                colp[j][cc] += __shfl_down(colp[j][cc], off, 64);
        }
    }
    if (yl == 0) {
#pragma unroll
        for (int cc = 0; cc < 4; cc++) {
            atomicAdd(&PS[d * 16 + c0 + cc], v2d[cc]);
#pragma unroll
            for (int j = 0; j < 8; j++)
                atomicAdd(&P[(d * 8 + j) * 16 + c0 + cc], colp[j][cc]);
            if (half == 0) P0[d * 16 + c0 + cc] = colp[0][cc];
        }
    }
}

// fproj stage 2: expand partials into theta=pi/2 outputs.
__global__ __launch_bounds__(256) void fproj2_k(
    const float* __restrict__ P, const float* __restrict__ PS,
    const float* __restrict__ P0, const int* __restrict__ flagp,
    void* __restrict__ out)
{
    const int bf = *flagp;
    const int d = blockIdx.x;
    const int tid = threadIdx.x;
    for (int i = tid; i < 2048; i += 256) {
        int c = i >> 7, u = i & 127;
        float v;
        if (u == 0)        v = P0[d * 16 + c];
        else if (u < 4)    v = P[(d * 8 + u) * 16 + c];
        else if (u >= 124) v = P[(d * 8 + (u - 120)) * 16 + c];
        else               v = PS[d * 16 + c];
        int oi = (c * 2 + 1) * 16384 + d * 128 + u;
        if (bf) ((u16*)out)[oi] = f2bf(v); else ((float*)out)[oi] = v;
    }
}

extern "C" void kernel_launch(void* const* d_in, const int* in_sizes, int n_in,
                              void* d_out, int out_size, void* d_ws, size_t ws_size,
                              hipStream_t stream)
{
    if (ws_size < WS_NEED) {
        sentinel_k<<<(out_size + 255) / 256, 256, 0, stream>>>((u16*)d_out, out_size);
        return;
    }
    const void* proj = d_in[0];
    const void* w1 = d_in[1]; const void* b1 = d_in[2];
    const void* w2 = d_in[3]; const void* b2 = d_in[4];
    const void* w3 = d_in[5]; const void* b3 = d_in[6];
    const void* w4 = d_in[7]; const void* b4 = d_in[8];

    float* I_A  = (float*)d_ws;
    float* I_B  = I_A + IN_ELEMS;
    float* I_XB = I_B + IN_ELEMS;
    u16*   M_A  = (u16*)(I_XB + IN_ELEMS);
    u16*   M_B  = M_A + MN_ELEMS;
    u16*   M_XB = M_B + MN_ELEMS;
    float* st    = (float*)(M_XB + MN_ELEMS);   // 256
    int*   flag  = (int*)(st + 256);            // 16
    float* biasf = (float*)(flag + 16);         // 64
    float* w2d   = biasf + 64;                  // 9216
    float* P     = w2d + 9216;                  // 16384
    float* PS    = P + 16384;                   // 2048
    float* P0    = PS + 2048;                   // 2048
    u16*   afrag = (u16*)(P0 + 2048);           // 36864

    wprep_prep_k<<<647, 256, 0, stream>>>(w1, w2, w3, w4, b1, b2, b3, b4, proj,
                                          st, flag, biasf, w2d, P, afrag, I_A, M_A);

    dim3 lg(1280), cb(256);
    // L1: conv1 on vol0 (no norm).        A -> B, stats st0
    layer_k<0,0,0><<<lg, cb, 0, stream>>>(I_A, M_A, proj, st, flag,
                                          w2d + 0,    afrag + 0,     biasf + 0,
                                          I_B, M_B, nullptr, nullptr, st + 0);
    // L2: conv2 on relu(IN_st0(y1)).      B -> A, stats st1
    layer_k<1,0,0><<<lg, cb, 0, stream>>>(I_B, M_B, proj, st + 0, flag,
                                          w2d + 2304, afrag + 9216,  biasf + 16,
                                          I_A, M_A, nullptr, nullptr, st + 64);
    // L3: conv3 on XB=relu(IN_st1(y2)+proj); materialize XB.  A -> B, stats st2
    layer_k<1,1,1><<<lg, cb, 0, stream>>>(I_A, M_A, proj, st + 64, flag,
                                          w2d + 4608, afrag + 18432, biasf + 32,
                                          I_B, M_B, I_XB, M_XB, st + 128);
    // L4: conv4 on relu(IN_st2(y3)).      B -> A, stats st3
    layer_k<1,0,0><<<lg, cb, 0, stream>>>(I_B, M_B, proj, st + 128, flag,
                                          w2d + 6912, afrag + 27648, biasf + 48,
                                          I_A, M_A, nullptr, nullptr, st + 192);
    // projection: raw y4 in A, residual XB
    fproj1_k<<<256, cb, 0, stream>>>(I_A, I_XB, M_A, M_XB, st + 192, flag, d_out, P, PS, P0);
    fproj2_k<<<128, cb, 0, stream>>>(P, PS, P0, flag, d_out);
}

// Round 3
// 200.954 us; speedup vs baseline: 1.1467x; 1.0522x over previous
//
#include <hip/hip_runtime.h>

// GeometryTransformation: backproject(theta=0) -> 2x resblock(conv3d 16->16 3^3,
// InstanceNorm, ReLU, residual) -> forward-project at theta in {0, pi/2}.
//
// Round-11: interior de-straggled. R10 counters showed layer_k (42us x4) with
// occ 22%/VALU 19%: a ~7us dense phase then a ~35us tail = the 256 interior
// blocks at 1 block/CU, 1 wave/SIMD (no latency hiding). Interior now runs
// 1024 blocks of 16-y (thread=(y,c), rows padded to 20f for aligned b128 row
// loads, coalesced b32 stores), 144 FMA/thread, backfilled ~4/CU in the tail.
// Global stats atomics spread over 8 banks (contention 1280 -> 160 per addr);
// consumers sum the 8 banks. Mini path math unchanged; interior FMA order
// (kz,ky,ci ascending) preserved bitwise. grid 1280 -> 2048 per layer.
// Math identical to round-10 (passed, absmax 4.0).

typedef unsigned short u16;
typedef unsigned int   u32;
using s16x8 = __attribute__((ext_vector_type(8))) short;
using f32x4 = __attribute__((ext_vector_type(4))) float;

#define IN_ELEMS 262144        // 128*128*16 fp32 interior
#define MN_ELEMS 4194304       // 128*128*16*16 u16 mini
#define WS_NEED  28508480ull

__device__ __forceinline__ float bf2f(u16 h) {
    union { u32 u; float f; } v; v.u = ((u32)h) << 16; return v.f;
}
__device__ __forceinline__ u16 f2bf(float f) {
    union { float f; u32 u; } v; v.f = f;
    u32 u = v.u;
    return (u16)((u + 0x7fffu + ((u >> 16) & 1u)) >> 16);
}
__device__ __forceinline__ float ldin(const void* p, int i, int bf) {
    return bf ? bf2f(((const u16*)p)[i]) : ((const float*)p)[i];
}
__device__ __forceinline__ u16 ldbf(const void* p, int i, int bf) {
    return bf ? ((const u16*)p)[i] : f2bf(((const float*)p)[i]);
}
__device__ __forceinline__ void unpack8(uint4 a, float* f) {
    u32 w[4] = {a.x, a.y, a.z, a.w};
#pragma unroll
    for (int i = 0; i < 4; i++) {
        f[2*i]   = bf2f((u16)(w[i] & 0xffff));
        f[2*i+1] = bf2f((u16)(w[i] >> 16));
    }
}
__device__ __forceinline__ void unpack4(uint2 a, float* f) {
    f[0] = bf2f((u16)(a.x & 0xffff)); f[1] = bf2f((u16)(a.x >> 16));
    f[2] = bf2f((u16)(a.y & 0xffff)); f[3] = bf2f((u16)(a.y >> 16));
}

// Sum the 8 contention-spread stat banks -> sA[0..15]=mean, sA[16..31]=rstd.
__device__ __forceinline__ void stat8(const float* __restrict__ stP, int tid,
                                      float* __restrict__ sA)
{
    const float inv = 1.f / 2097152.f;
    int c = tid & 15;
    float ssum = 0.f, qsum = 0.f;
#pragma unroll
    for (int b2 = 0; b2 < 8; b2++) {
        ssum += stP[b2 * 32 + c];
        qsum += stP[b2 * 32 + 16 + c];
    }
    float m = ssum * inv;
    sA[tid] = (tid < 16) ? m : rsqrtf(qsum * inv - m * m + 1e-5f);
}

__global__ void sentinel_k(u16* __restrict__ out, int n)
{
    int i = blockIdx.x * 256 + threadIdx.x;
    if (i < n) out[i] = 0x4640;
}

// ---------------------------------------------------------------------------
// Merged one-shot prep. 647 blocks:
//  0..17  : afrag  18     : st zero + flag + biasf  19..98 : zero P/PS/P0
//  99..134: w2d    135..646: layer-0 state.
// ---------------------------------------------------------------------------
__global__ __launch_bounds__(256) void wprep_prep_k(
    const void* __restrict__ w0, const void* __restrict__ w1,
    const void* __restrict__ w2, const void* __restrict__ w3,
    const void* __restrict__ b0, const void* __restrict__ b1,
    const void* __restrict__ b2, const void* __restrict__ b3,
    const void* __restrict__ proj,
    float* __restrict__ st, int* __restrict__ flag,
    float* __restrict__ biasf, float* __restrict__ w2d,
    float* __restrict__ pz, u16* __restrict__ afrag,
    float* __restrict__ I0, u16* __restrict__ M0)
{
    const int tid = threadIdx.x;
    const u16* pp = (const u16*)w0;
    int cnt = 0;
    for (int i = 0; i < 32; i++) {
        int e = (pp[2 * i] >> 7) & 0xFF;
        if (e >= 64 && e <= 130) cnt++;
    }
    const int bf = (cnt >= 24) ? 1 : 0;
    const void* WS[4] = {w0, w1, w2, w3};
    const void* BS[4] = {b0, b1, b2, b3};
    const int b = blockIdx.x;

    if (b >= 135) {
        const int bb = b - 135;
        const int d = bb >> 2;
        const int ys = (bb & 3) * 32;
        for (int i = tid; i < 512; i += 256) {
            int y = ys + (i >> 4), c = i & 15;
            I0[(d * 128 + y) * 16 + c] = ldin(proj, c * 16384 + d * 128 + y, bf);
        }
        for (int i = tid; i < 1024; i += 256) {
            int y = ys + (i >> 5), x = (i >> 1) & 15, hh = i & 1;
            bool on = (x <= 4) | (x == 7) | (x >= 8 && x < 12);
            u32 pw[4] = {0u, 0u, 0u, 0u};
            if (on) {
#pragma unroll
                for (int j = 0; j < 4; j++) {
                    int c0 = hh * 8 + 2 * j;
                    u16 a = f2bf(ldin(proj, c0 * 16384 + d * 128 + y, bf));
                    u16 bb2 = f2bf(ldin(proj, (c0 + 1) * 16384 + d * 128 + y, bf));
                    pw[j] = (u32)a | ((u32)bb2 << 16);
                }
            }
            *(uint4*)(M0 + ((d * 128 + y) << 8) + (x << 4) + hh * 8) =
                make_uint4(pw[0], pw[1], pw[2], pw[3]);
        }
        return;
    }

    if (b < 18) {
        int gi = b * 256 + tid;               // < 4608
        int L = gi / 1152, r = gi - L * 1152;
        int fi = r >> 6, l = r & 63;
        int kzky = fi >> 1, grp = fi & 1;
        int kz = kzky / 3, ky = kzky % 3;
        int n = l & 15, g = l >> 4, h = g & 1, kxs = g >> 1;
        int kx = grp * 2 + kxs;
        u16 v[8];
#pragma unroll
        for (int e = 0; e < 8; e++) {
            int ci = h * 8 + e;
            v[e] = (kx <= 2) ? ldbf(WS[L], n * 432 + ci * 27 + kz * 9 + ky * 3 + kx, bf)
                             : (u16)0;
        }
#pragma unroll
        for (int e = 0; e < 8; e++) afrag[gi * 8 + e] = v[e];
    } else if (b == 18) {
        for (int i = tid; i < 1024; i += 256) st[i] = 0.f;
        if (tid == 0) *flag = bf;
        if (tid < 64) biasf[tid] = ldin(BS[tid >> 4], tid & 15, bf);
    } else if (b < 99) {
        int i = (b - 19) * 256 + tid;         // < 20480
        pz[i] = 0.f;
    } else {
        int gi = (b - 99) * 256 + tid;        // < 9216
        int L = gi / 2304, r = gi - L * 2304;
        int tap = r >> 8, ci = (r >> 4) & 15, co = r & 15;
        int kz = tap / 3, ky = tap % 3;
        float s = 0.f;
#pragma unroll
        for (int kx = 0; kx < 3; kx++)
            s += ldin(WS[L], (co * 16 + ci) * 27 + kz * 9 + ky * 3 + kx, bf);
        w2d[gi] = s;
    }
}

// ---------------------------------------------------------------------------
// Fused layer. Blocks 0..1023: interior 2D conv, block=(d, 16-y slice).
// Blocks 1024..2047: mini MFMA conv (z, yt). NORM: staging normalizes the raw
// previous-layer output (8-bank stats). RES: +proj residual. WXB: write XB.
// ---------------------------------------------------------------------------
template <int NORM, int RES, int WXB>
__global__ __launch_bounds__(256) void layer_k(
    const float* __restrict__ Iin, const u16* __restrict__ Min,
    const void* __restrict__ proj, const float* __restrict__ stP,
    const int* __restrict__ flagp,
    const float* __restrict__ w2dL, const u16* __restrict__ afragL,
    const float* __restrict__ biasL,
    float* __restrict__ Iout, u16* __restrict__ Mout,
    float* __restrict__ IXB, u16* __restrict__ MXB,
    float* __restrict__ st_out)
{
    // interior: wsl 2304 f | pin 3*18*20=1080 f | sred 32 f | sA 32 f (13792 B)
    // mini:     stage 54*256 u16 (27648 B) | sred 32 f | sA 32 f (27904 B)
    __shared__ __align__(16) char smem_raw[27904];
    const int tid = threadIdx.x;
    const int bf = RES ? *flagp : 0;
    const int bank = (blockIdx.x & 7) * 32;

    if (blockIdx.x < 1024) {
        float* smem = (float*)smem_raw;
        float* wsl  = smem;          // 2304
        float* pin  = smem + 2304;   // 1080 (rows padded to 20 for b128)
        float* sred = smem + 3384;   // 32
        float* sA   = smem + 3416;   // 32
        const int d  = blockIdx.x >> 3;
        const int yo = (blockIdx.x & 7) * 16;
        if (tid < 32) {
            sred[tid] = 0.f;
            if (NORM) stat8(stP, tid, sA);
        }
        for (int i = tid; i < 576; i += 256)
            *(float4*)(wsl + i * 4) = *(const float4*)(w2dL + i * 4);
        if (NORM) __syncthreads();           // sA ready before pin staging
        for (int i = tid; i < 864; i += 256) {
            int p = i / 288, r = i - p * 288;
            int row = r >> 4, c = r & 15;
            int zz = d + p - 1, gy = yo + row - 1;
            float v = 0.f;
            if ((unsigned)zz < 128u && (unsigned)gy < 128u) {
                v = Iin[(zz * 128 + gy) * 16 + c];
                if (NORM) {
                    float res = RES ? ldin(proj, c * 16384 + zz * 128 + gy, bf) : 0.f;
                    v = fmaxf((v - sA[c]) * sA[16 + c] + res, 0.f);
                }
                if (WXB && p == 1 && row >= 1 && row <= 16)
                    IXB[(d * 128 + gy) * 16 + c] = v;
            }
            pin[p * 360 + row * 20 + c] = v;
        }
        __syncthreads();

        const int c = tid & 15, yl = tid >> 4;   // 16 c x 16 y
        float acc = biasL[c];
#pragma unroll
        for (int kz = 0; kz < 3; kz++) {
#pragma unroll
            for (int ky = 0; ky < 3; ky++) {
                const float4* rowb = (const float4*)(pin + kz * 360 + (yl + ky) * 20);
                const float* wrow = wsl + (kz * 3 + ky) * 256 + c;
#pragma unroll
                for (int qd = 0; qd < 4; qd++) {
                    float4 vq = rowb[qd];
                    acc = fmaf(vq.x, wrow[(qd * 4 + 0) * 16], acc);
                    acc = fmaf(vq.y, wrow[(qd * 4 + 1) * 16], acc);
                    acc = fmaf(vq.z, wrow[(qd * 4 + 2) * 16], acc);
                    acc = fmaf(vq.w, wrow[(qd * 4 + 3) * 16], acc);
                }
            }
        }
        Iout[(d * 128 + yo + yl) * 16 + c] = acc;
        float s = acc, q = acc * acc;
        s += __shfl_xor(s, 16, 64); s += __shfl_xor(s, 32, 64);
        q += __shfl_xor(q, 16, 64); q += __shfl_xor(q, 32, 64);
        if ((tid & 63) < 16) {
            atomicAdd(&sred[c], s);
            atomicAdd(&sred[16 + c], q);
        }
        __syncthreads();
        if (tid < 32) atomicAdd(&st_out[bank + tid], 120.f * sred[tid]);
        return;
    }

    // ---------------- mini path ----------------
    u16*   stage = (u16*)smem_raw;
    float* sred  = (float*)(smem_raw + 27648);
    float* sA    = (float*)(smem_raw + 27776);
    const int mb = blockIdx.x - 1024;
    const int z  = mb & 127;
    const int yt = mb >> 7;
    const int l = tid & 63, w = tid >> 6;
    const int n = l & 15, g = l >> 4, h = g & 1, kxs = g >> 1;
    const int y0 = yt * 16 + w * 4;
    const int y0b = yt * 16;

    if (tid < 32) {
        sred[tid] = 0.f;
        if (NORM) stat8(stP, tid, sA);
    }
    if (NORM) __syncthreads();               // sA ready before staging

    // Stage 54 rows (3 z-planes x 18 y-rows), 512B each. NORM applies the
    // fused normalize (ghosts x=4,7 from interior; zeros elsewhere).
    for (int i = tid; i < 1728; i += 256) {
        int r = i >> 5, p = i & 31;
        int kz = r / 18, yr = r - kz * 18;
        int gz = z + kz - 1, gy = y0b + yr - 1;
        uint4 v = make_uint4(0u, 0u, 0u, 0u);
        bool inb = ((unsigned)gz < 128u) & ((unsigned)gy < 128u);
        if (!NORM) {
            if (inb) v = *(const uint4*)(Min + (((gz << 7) + gy) << 8) + p * 8);
        } else {
            int x = p >> 1, hh = p & 1;
            bool realc = (x < 4) | (x >= 8 && x < 12);
            bool ghost = (x == 4) | (x == 7);
            if (inb & (realc | ghost)) {
                float f[8];
                if (realc) {
                    uint4 raw = *(const uint4*)(Min + (((gz << 7) + gy) << 8) + p * 8);
                    unpack8(raw, f);
                } else {
                    const float* ip = Iin + ((gz * 128 + gy) * 16 + hh * 8);
                    float4 a  = *(const float4*)(ip);
                    float4 b2 = *(const float4*)(ip + 4);
                    f[0] = a.x;  f[1] = a.y;  f[2] = a.z;  f[3] = a.w;
                    f[4] = b2.x; f[5] = b2.y; f[6] = b2.z; f[7] = b2.w;
                }
                float vals[8];
#pragma unroll
                for (int j = 0; j < 8; j++) {
                    int c = hh * 8 + j;
                    float res = RES ? ldin(proj, c * 16384 + gz * 128 + gy, bf) : 0.f;
                    vals[j] = fmaxf((f[j] - sA[c]) * sA[16 + c] + res, 0.f);
                }
                u32 pw[4];
#pragma unroll
                for (int j = 0; j < 4; j++)
                    pw[j] = (u32)f2bf(vals[2*j]) | ((u32)f2bf(vals[2*j+1]) << 16);
                v = make_uint4(pw[0], pw[1], pw[2], pw[3]);
            }
            if (WXB && kz == 1 && yr >= 1 && yr <= 16)
                *(uint4*)(MXB + (((z << 7) + gy) << 8) + p * 8) = v;
        }
        *(uint4*)(stage + r * 256 + p * 8) = v;
    }

    s16x8 af[18];
#pragma unroll
    for (int fi = 0; fi < 18; fi++)
        af[fi] = *(const s16x8*)(afragL + (fi * 64 + l) * 8);
    f32x4 binit = *(const f32x4*)(biasL + g * 4);
    __syncthreads();

    f32x4 acc[4];
#pragma unroll
    for (int yl = 0; yl < 4; yl++) acc[yl] = binit;

    const int x0c = n + kxs - 1;
    const int x1c = x0c + 2;
    const bool v0ok = (unsigned)x0c < 16u;
    const bool v1ok = (unsigned)x1c < 16u;

#pragma unroll
    for (int kz = 0; kz < 3; kz++) {
#pragma unroll
        for (int yin = 0; yin < 6; yin++) {
            const u16* rowp = stage + (kz * 18 + (w << 2) + yin) * 256 + h * 8;
            uint4 q0 = make_uint4(0u, 0u, 0u, 0u);
            uint4 q1 = make_uint4(0u, 0u, 0u, 0u);
            if (v0ok) q0 = *(const uint4*)(rowp + (x0c << 4));
            if (v1ok) q1 = *(const uint4*)(rowp + (x1c << 4));
            s16x8 f0 = __builtin_bit_cast(s16x8, q0);
            s16x8 f1 = __builtin_bit_cast(s16x8, q1);
#pragma unroll
            for (int ky = 0; ky < 3; ky++) {
                const int yl = yin - ky;
                if (yl >= 0 && yl < 4) {
                    acc[yl] = __builtin_amdgcn_mfma_f32_16x16x32_bf16(af[(kz * 3 + ky) * 2],     f0, acc[yl], 0, 0, 0);
                    acc[yl] = __builtin_amdgcn_mfma_f32_16x16x32_bf16(af[(kz * 3 + ky) * 2 + 1], f1, acc[yl], 0, 0, 0);
                }
            }
        }
    }

    const float inc = (((n >> 2) & 1) == 0) ? 1.f : 0.f;
    float sr[4] = {0.f, 0.f, 0.f, 0.f}, qr[4] = {0.f, 0.f, 0.f, 0.f};
#pragma unroll
    for (int yl = 0; yl < 4; yl++) {
        const int gy = y0 + yl;
        u32 lo = (u32)f2bf(acc[yl][0]) | ((u32)f2bf(acc[yl][1]) << 16);
        u32 hi = (u32)f2bf(acc[yl][2]) | ((u32)f2bf(acc[yl][3]) << 16);
        *(uint2*)(Mout + (((z << 7) + gy) << 8) + (n << 4) + g * 4) = make_uint2(lo, hi);
#pragma unroll
        for (int r = 0; r < 4; r++) {
            sr[r] += inc * acc[yl][r];
            qr[r] = fmaf(inc * acc[yl][r], acc[yl][r], qr[r]);
        }
    }
#pragma unroll
    for (int off = 1; off < 16; off <<= 1) {
#pragma unroll
        for (int r = 0; r < 4; r++) {
            sr[r] += __shfl_down(sr[r], off, 16);
            qr[r] += __shfl_down(qr[r], off, 16);
        }
    }
    __syncthreads();
    if (n == 0) {
#pragma unroll
        for (int r = 0; r < 4; r++) {
            atomicAdd(&sred[g * 4 + r], sr[r]);
            atomicAdd(&sred[16 + g * 4 + r], qr[r]);
        }
    }
    __syncthreads();
    if (tid < 32) atomicAdd(&st_out[bank + tid], sred[tid]);
}

// fproj stage 1: 256 blocks = (d, y-half). vol2 = relu((y4-m)s + xb).
__global__ __launch_bounds__(256) void fproj1_k(
    const float* __restrict__ I4, const float* __restrict__ IXB,
    const u16* __restrict__ M4, const u16* __restrict__ MXB,
    const float* __restrict__ stL, const int* __restrict__ flagp,
    void* __restrict__ out,
    float* __restrict__ P, float* __restrict__ PS, float* __restrict__ P0)
{
    __shared__ float sA[32];
    const int bf = *flagp;
    const int d = blockIdx.x >> 1;
    const int half = blockIdx.x & 1;
    const int tid = threadIdx.x;
    if (tid < 32) stat8(stL, tid, sA);
    __syncthreads();

    const int yl = tid & 63, y = half * 64 + yl;
    const int h = tid >> 6, c0 = h * 4;

    float v2d[4], row[4];
    {
        const int e = (d * 128 + y) * 16 + c0;
        float4 a = *(const float4*)(I4 + e);
        float4 x = *(const float4*)(IXB + e);
        float ia[4] = {a.x, a.y, a.z, a.w};
        float xa[4] = {x.x, x.y, x.z, x.w};
#pragma unroll
        for (int cc = 0; cc < 4; cc++) {
            int c = c0 + cc;
            v2d[cc] = fmaxf((ia[cc] - sA[c]) * sA[16 + c] + xa[cc], 0.f);
            row[cc] = 120.f * v2d[cc];
        }
    }
    float colp[8][4];
#pragma unroll
    for (int j = 0; j < 8; j++) {
        const int m = (j < 4) ? j : j + 4;
        const int e = ((d * 128 + y) << 8) + (m << 4) + c0;
        float f4[4], fx[4];
        unpack4(*(const uint2*)(M4 + e), f4);
        unpack4(*(const uint2*)(MXB + e), fx);
#pragma unroll
        for (int cc = 0; cc < 4; cc++) {
            int c = c0 + cc;
            float v = fmaxf((f4[cc] - sA[c]) * sA[16 + c] + fx[cc], 0.f);
            row[cc] += v;
            colp[j][cc] = v;
        }
    }
#pragma unroll
    for (int cc = 0; cc < 4; cc++) {
        int oi = ((c0 + cc) * 2) * 16384 + d * 128 + y;
        if (bf) ((u16*)out)[oi] = f2bf(row[cc]); else ((float*)out)[oi] = row[cc];
    }
#pragma unroll
    for (int off = 1; off < 64; off <<= 1) {
#pragma unroll
        for (int cc = 0; cc < 4; cc++) {
            v2d[cc] += __shfl_down(v2d[cc], off, 64);
#pragma unroll
            for (int j = 0; j < 8; j++)
                colp[j][cc] += __shfl_down(colp[j][cc], off, 64);
        }
    }
    if (yl == 0) {
#pragma unroll
        for (int cc = 0; cc < 4; cc++) {
            atomicAdd(&PS[d * 16 + c0 + cc], v2d[cc]);
#pragma unroll
            for (int j = 0; j < 8; j++)
                atomicAdd(&P[(d * 8 + j) * 16 + c0 + cc], colp[j][cc]);
            if (half == 0) P0[d * 16 + c0 + cc] = colp[0][cc];
        }
    }
}

// fproj stage 2: expand partials into theta=pi/2 outputs.
__global__ __launch_bounds__(256) void fproj2_k(
    const float* __restrict__ P, const float* __restrict__ PS,
    const float* __restrict__ P0, const int* __restrict__ flagp,
    void* __restrict__ out)
{
    const int bf = *flagp;
    const int d = blockIdx.x;
    const int tid = threadIdx.x;
    for (int i = tid; i < 2048; i += 256) {
        int c = i >> 7, u = i & 127;
        float v;
        if (u == 0)        v = P0[d * 16 + c];
        else if (u < 4)    v = P[(d * 8 + u) * 16 + c];
        else if (u >= 124) v = P[(d * 8 + (u - 120)) * 16 + c];
        else               v = PS[d * 16 + c];
        int oi = (c * 2 + 1) * 16384 + d * 128 + u;
        if (bf) ((u16*)out)[oi] = f2bf(v); else ((float*)out)[oi] = v;
    }
}

extern "C" void kernel_launch(void* const* d_in, const int* in_sizes, int n_in,
                              void* d_out, int out_size, void* d_ws, size_t ws_size,
                              hipStream_t stream)
{
    if (ws_size < WS_NEED) {
        sentinel_k<<<(out_size + 255) / 256, 256, 0, stream>>>((u16*)d_out, out_size);
        return;
    }
    const void* proj = d_in[0];
    const void* w1 = d_in[1]; const void* b1 = d_in[2];
    const void* w2 = d_in[3]; const void* b2 = d_in[4];
    const void* w3 = d_in[5]; const void* b3 = d_in[6];
    const void* w4 = d_in[7]; const void* b4 = d_in[8];

    float* I_A  = (float*)d_ws;
    float* I_B  = I_A + IN_ELEMS;
    float* I_XB = I_B + IN_ELEMS;
    u16*   M_A  = (u16*)(I_XB + IN_ELEMS);
    u16*   M_B  = M_A + MN_ELEMS;
    u16*   M_XB = M_B + MN_ELEMS;
    float* st    = (float*)(M_XB + MN_ELEMS);   // 1024 (4 layers x 8 banks x 32)
    int*   flag  = (int*)(st + 1024);           // 16
    float* biasf = (float*)(flag + 16);         // 64
    float* w2d   = biasf + 64;                  // 9216
    float* P     = w2d + 9216;                  // 16384
    float* PS    = P + 16384;                   // 2048
    float* P0    = PS + 2048;                   // 2048
    u16*   afrag = (u16*)(P0 + 2048);           // 36864

    wprep_prep_k<<<647, 256, 0, stream>>>(w1, w2, w3, w4, b1, b2, b3, b4, proj,
                                          st, flag, biasf, w2d, P, afrag, I_A, M_A);

    dim3 lg(2048), cb(256);
    // L1: conv1 on vol0 (no norm).        A -> B, stats st0
    layer_k<0,0,0><<<lg, cb, 0, stream>>>(I_A, M_A, proj, st, flag,
                                          w2d + 0,    afrag + 0,     biasf + 0,
                                          I_B, M_B, nullptr, nullptr, st + 0);
    // L2: conv2 on relu(IN_st0(y1)).      B -> A, stats st1
    layer_k<1,0,0><<<lg, cb, 0, stream>>>(I_B, M_B, proj, st + 0, flag,
                                          w2d + 2304, afrag + 9216,  biasf + 16,
                                          I_A, M_A, nullptr, nullptr, st + 256);
    // L3: conv3 on XB=relu(IN_st1(y2)+proj); materialize XB.  A -> B, stats st2
    layer_k<1,1,1><<<lg, cb, 0, stream>>>(I_A, M_A, proj, st + 256, flag,
                                          w2d + 4608, afrag + 18432, biasf + 32,
                                          I_B, M_B, I_XB, M_XB, st + 512);
    // L4: conv4 on relu(IN_st2(y3)).      B -> A, stats st3
    layer_k<1,0,0><<<lg, cb, 0, stream>>>(I_B, M_B, proj, st + 512, flag,
                                          w2d + 6912, afrag + 27648, biasf + 48,
                                          I_A, M_A, nullptr, nullptr, st + 768);
    // projection: raw y4 in A, residual XB
    fproj1_k<<<256, cb, 0, stream>>>(I_A, I_XB, M_A, M_XB, st + 768, flag, d_out, P, PS, P0);
    fproj2_k<<<128, cb, 0, stream>>>(P, PS, P0, flag, d_out);
}